// Round 7
// baseline (91.525 us; speedup 1.0000x reference)
//
#include <hip/hip_runtime.h>
#include <hip/hip_bf16.h>

typedef __attribute__((ext_vector_type(8))) short short8_t;
typedef __attribute__((ext_vector_type(4))) float f32x4;

#define BATCH 16
#define CIN   512
#define COUT  512
#define TT    4096
#define BKT   64
#define NKT   (CIN / BKT)   // 8 K-steps

// pack 2 f32 -> u32 of 2 bf16 (RNE); pairs into v_cvt_pk_bf16_f32
__device__ __forceinline__ uint pk2(float a, float b) {
    ushort lo = __builtin_bit_cast(ushort, __float2bfloat16(a));
    ushort hi = __builtin_bit_cast(ushort, __float2bfloat16(b));
    return (uint)lo | ((uint)hi << 16);
}

#define SCHEDB() __builtin_amdgcn_sched_barrier(0)
#define WAIT_VM4() do { asm volatile("s_waitcnt vmcnt(4)" ::: "memory"); SCHEDB(); } while (0)
#define BARRIER() do { SCHEDB(); __builtin_amdgcn_s_barrier(); SCHEDB(); } while (0)

// direct global->LDS DMA, 16B per lane; LDS dest must be linear (base+lane*16)
#define GLOAD_LDS16(G, L) \
    __builtin_amdgcn_global_load_lds((const __attribute__((address_space(1))) void*)(G), \
                                     (__attribute__((address_space(3))) void*)(L), 16, 0, 0)

// ---------------------------------------------------------------------------
// Pre-pass: W (fp32 [512][512]) -> bf16 MFMA-fragment order:
//   Wb[bm][ksg][g][r][8k], bm=m>>4, r=m&15, ksg=k>>5, g=(k>>3)&3
// One A fragment = one coalesced dwordx4.
// ---------------------------------------------------------------------------
extern "C" __global__ __launch_bounds__(256)
void wconv(const float* __restrict__ W, ushort* __restrict__ Wb)
{
    const int i  = blockIdx.x * 256 + threadIdx.x;   // [0, 65536)
    const int m  = i >> 7;
    const int k0 = (i & 127) * 4;
    const float4 v = *(const float4*)(W + (size_t)m * CIN + k0);
    const int bm = m >> 4, r = m & 15;
    const int ksg = k0 >> 5, g = (k0 >> 3) & 3, k7 = k0 & 7;
    uint2 q;
    q.x = pk2(v.x, v.y);
    q.y = pk2(v.z, v.w);
    *(uint2*)&Wb[(size_t)bm * 8192 + ksg * 512 + g * 128 + r * 8 + k7] = q;
}

// ---------------------------------------------------------------------------
// Main GEMM: tile 128m x 64n, BK=64 (8 steps), 4 waves (wave 32m x 64n).
// B: staged as RAW fp32 via global_load_lds into 3 rotating LDS buffers
//    ([64k][64t] f32, 16 KiB each). Source addresses pre-swizzled:
//    LDS[k][c] holds global col-group c ^ s(k), s(k) = ((k>>3)*5)&7 (16B
//    granule XOR) -> every fragment ds_read_b32 lands 2 lanes/bank (free).
// A: fragment-direct global loads from Wb (L2-hot), 2-deep in regs.
// Sync: counted vmcnt(4) + raw s_barrier -- tiles kt+1, kt+2 stay in flight
// across barriers; cvt fp32->bf16 happens at fragment-read time.
// ---------------------------------------------------------------------------
template<bool WSB>
__global__ __launch_bounds__(256)
void conv2x1_gemm(const float* __restrict__ pre, const float* __restrict__ W,
                  const ushort* __restrict__ Wb,
                  const float* __restrict__ bias, float* __restrict__ out)
{
    __shared__ float LBUF[3 * 4096];   // 3 x 16 KiB fp32 B tiles

    const int tid  = threadIdx.x;
    const int lane = tid & 63;
    const int wv   = tid >> 6;          // wave = m-strip [0,4)
    const int g    = lane >> 4;
    const int l15  = lane & 15;

    // XCD-chunked bijective swizzle (4096 = 8*512); ids id..id+3 share a
    // B-panel (same bb, ti) on one XCD's L2.
    const int id   = ((blockIdx.x & 7) << 9) | (blockIdx.x >> 3);
    const int mblk = id & 3;
    const int ti   = (id >> 2) & 63;
    const int bb   = id >> 8;

    const int m0 = mblk << 7;   // [0,512) step 128
    const int t0 = ti << 6;     // [0,4096) step 64

    const float* preB   = pre + (size_t)bb * ((size_t)CIN * TT);
    const int    bmBase = (m0 >> 4) + wv * 2;

    short8_t afA[2][2], afB[2][2];   // A fragments, 2-deep

    f32x4 acc[2][4];
#pragma unroll
    for (int i = 0; i < 2; ++i)
#pragma unroll
        for (int j = 0; j < 4; ++j) acc[i][j] = (f32x4)0.0f;

    // ---- B stage: 4 global_load_lds per wave; rows wv*16..+15, linear LDS ----
#define STAGE(KT, BUF) do { \
    _Pragma("unroll") \
    for (int i = 0; i < 4; ++i) { \
        const int kb = wv*16 + i*4; \
        const int k  = kb + (lane >> 4); \
        const int sw = (((((KT)*BKT + k) >> 3) * 5) & 7); \
        const float* gsrc = preB + (size_t)((KT)*BKT + k) * TT + t0 \
                            + (((lane & 15) ^ sw) << 2); \
        float* ldst = &LBUF[(BUF)*4096 + kb*64 + (lane << 2)]; \
        GLOAD_LDS16(gsrc, ldst); \
    } } while (0)

#define LOAD_A(KT, AF) do { \
    if constexpr (WSB) { \
        _Pragma("unroll") \
        for (int ks = 0; ks < 2; ++ks) \
            _Pragma("unroll") \
            for (int mi = 0; mi < 2; ++mi) \
                AF[ks][mi] = *(const short8_t*)(Wb + (size_t)(bmBase + mi) * 8192 \
                                                + ((KT)*2 + ks) * 512 + g * 128 + l15 * 8); \
    } else { \
        _Pragma("unroll") \
        for (int ks = 0; ks < 2; ++ks) \
            _Pragma("unroll") \
            for (int mi = 0; mi < 2; ++mi) { \
                const float* ab = W + (size_t)(m0 + wv*32 + mi*16 + l15) * CIN \
                                  + (KT)*BKT + ks*32 + g*8; \
                const float4 u0 = *(const float4*)ab; \
                const float4 u1 = *(const float4*)(ab + 4); \
                uint4 qq; \
                qq.x = pk2(u0.x, u0.y); qq.y = pk2(u0.z, u0.w); \
                qq.z = pk2(u1.x, u1.y); qq.w = pk2(u1.z, u1.w); \
                AF[ks][mi] = __builtin_bit_cast(short8_t, qq); \
            } \
    } } while (0)

    // ---- compute one K-step from LDS buffer BUF using fragments AF ----
#define COMPUTE(BUF, AF) do { \
    const float* bb0 = &LBUF[(BUF)*4096]; \
    _Pragma("unroll") \
    for (int ks = 0; ks < 2; ++ks) { \
        _Pragma("unroll") \
        for (int ni = 0; ni < 4; ++ni) { \
            const int n4 = ni*4 + (l15 >> 2); \
            const int sw = (((ks*4 + g) * 5) & 7); \
            const float* bp = bb0 + (ks*32 + g*8)*64 + ((n4 ^ sw) << 2) + (l15 & 3); \
            uint4 q; \
            q.x = pk2(bp[0],   bp[64]); \
            q.y = pk2(bp[128], bp[192]); \
            q.z = pk2(bp[256], bp[320]); \
            q.w = pk2(bp[384], bp[448]); \
            const short8_t bf = __builtin_bit_cast(short8_t, q); \
            _Pragma("unroll") \
            for (int mi = 0; mi < 2; ++mi) \
                acc[mi][ni] = __builtin_amdgcn_mfma_f32_16x16x32_bf16(AF[ks][mi], bf, acc[mi][ni], 0, 0, 0); \
        } \
    } } while (0)

    // -------- prologue: FIFO = [s0, A0, s1, s2] --------
    STAGE(0, 0);
    LOAD_A(0, afA);
    STAGE(1, 1);
    STAGE(2, 2);

    // -------- main loop --------
    // invariant at iter kt wait: vmcnt(4) completes tile kt (and A(kt));
    // tiles kt+1, kt+2 remain in flight across the barrier.
#pragma unroll
    for (int kt = 0; kt < NKT; ++kt) {
        const int cur = kt % 3;
        WAIT_VM4();
        BARRIER();                        // tile kt visible to all waves
        if (kt + 1 < NKT) {
            if ((kt & 1) == 0) LOAD_A(kt + 1, afB);
            else               LOAD_A(kt + 1, afA);
        }
        if ((kt & 1) == 0) COMPUTE(cur, afA);
        else               COMPUTE(cur, afB);
        BARRIER();                        // all waves done reading buf cur
        if (kt + 3 < NKT) STAGE(kt + 3, cur);
    }

    // -------- epilogue: out = 2*(acc + bias) --------
    const int orow = m0 + wv*32 + g*4;     // + mi*16 + r
    float bv[2][4];
#pragma unroll
    for (int mi = 0; mi < 2; ++mi)
#pragma unroll
        for (int r = 0; r < 4; ++r)
            bv[mi][r] = bias[orow + mi*16 + r];

    float* outB = out + (size_t)bb * ((size_t)COUT * TT);
#pragma unroll
    for (int mi = 0; mi < 2; ++mi) {
#pragma unroll
        for (int ni = 0; ni < 4; ++ni) {
            const int t = t0 + ni*16 + l15;
#pragma unroll
            for (int r = 0; r < 4; ++r) {
                const int o = orow + mi*16 + r;
                outB[(size_t)o * TT + t] = 2.0f * (acc[mi][ni][r] + bv[mi][r]);
            }
        }
    }
}

extern "C" void kernel_launch(void* const* d_in, const int* in_sizes, int n_in,
                              void* d_out, int out_size, void* d_ws, size_t ws_size,
                              hipStream_t stream)
{
    const float* pre  = (const float*)d_in[0];   // [16, 512, 4096] fp32
    const float* Wp   = (const float*)d_in[1];   // [512, 512] fp32
    const float* bias = (const float*)d_in[2];   // [512] fp32
    float* out = (float*)d_out;                  // [16, 512, 4096] fp32

    const bool usews = (ws_size >= (size_t)(COUT * CIN * sizeof(ushort)));  // 512 KiB

    if (usews) {
        ushort* Wb = (ushort*)d_ws;
        hipLaunchKernelGGL(wconv, dim3(256), dim3(256), 0, stream, Wp, Wb);
        hipLaunchKernelGGL((conv2x1_gemm<true>), dim3(BATCH * 4 * 64), dim3(256), 0, stream,
                           pre, Wp, Wb, bias, out);
    } else {
        hipLaunchKernelGGL((conv2x1_gemm<false>), dim3(BATCH * 4 * 64), dim3(256), 0, stream,
                           pre, Wp, (const ushort*)nullptr, bias, out);
    }
}